// Round 2
// baseline (216.605 us; speedup 1.0000x reference)
//
#include <hip/hip_runtime.h>
#include <hip/hip_bf16.h>

// Problem constants
#define NROWS 65536      // 64*32*32
#define DIM   256
#define NCODE 1024
#define OUT_ELEMS 16777216  // NROWS*DIM

typedef __attribute__((ext_vector_type(8))) short bf16x8;
typedef __attribute__((ext_vector_type(4))) float f32x4;

__device__ __forceinline__ unsigned umin_(unsigned a, unsigned b) { return a < b ? a : b; }

// RNE float->bf16 (finite inputs) — must stay bit-identical across rounds
__device__ __forceinline__ unsigned short f2bf(float f) {
    unsigned b = __builtin_bit_cast(unsigned, f);
    return (unsigned short)((b + 0x7FFFu + ((b >> 16) & 1u)) >> 16);
}

// async global->LDS, 16B per lane: lane l deposits at lds_base + l*16
__device__ __forceinline__ void gload_lds16(const void* g, void* l) {
    __builtin_amdgcn_global_load_lds(
        (const __attribute__((address_space(1))) unsigned int*)g,
        (__attribute__((address_space(3))) unsigned int*)l, 16, 0, 0);
}

// ---------------------------------------------------------------------------
// K_prep: blocks 0..127: codebook fp32 -> bf16 in MFMA B-fragment order.
//   eb[((t*8+ks)*64 + lane)*8 + j] = e[n][k], n=t*16+(lane&15), k=ks*32+(lane>>4)*8+j
//   (tile t = 4096 shorts = 8 KB contiguous — exactly the LDS staging order)
// blocks 128..131: per-code squared norms + 0.25 key offset (fp32 exact).
// ---------------------------------------------------------------------------
__global__ __launch_bounds__(256)
void k_prep(const float* __restrict__ e, float* __restrict__ seb,
            unsigned short* __restrict__ eb) {
    int b = blockIdx.x;
    if (b < 128) {
        int g = b * 256 + threadIdx.x;   // 0 .. 32767
        int lane = g & 63;
        int ks   = (g >> 6) & 7;
        int t    = g >> 9;
        int n  = t * 16 + (lane & 15);
        int k0 = ks * 32 + (lane >> 4) * 8;
        const float* src = e + (size_t)n * DIM + k0;
        bf16x8 o;
        #pragma unroll
        for (int j = 0; j < 8; ++j) o[j] = (short)f2bf(src[j]);
        *(bf16x8*)(eb + (size_t)g * 8) = o;
    } else {
        int c = (b - 128) * 256 + threadIdx.x;
        const float4* r = (const float4*)(e + (size_t)c * DIM);
        float s = 0.f;
        #pragma unroll
        for (int i = 0; i < DIM / 4; ++i) {
            float4 v = r[i];
            s += v.x * v.x + v.y * v.y + v.z * v.z + v.w * v.w;
        }
        seb[c] = s + 0.25f;
    }
}

// ---------------------------------------------------------------------------
// K1: MFMA distance-argmin, LDS-shared B, COUNTED-VMCNT RING PIPELINE (R2).
// Grid 1024 blocks x 128 thr (2 waves); wave w owns rows [row0+w*32, +32)
// as 2 stripes x 16.  B staged per 16-code TILE (8 KB) into a 4-slot LDS
// ring (32 KB), prefetch depth 3, via global_load_lds(16B).  Per tile:
//   s_waitcnt vmcnt(8)   <- own stage-group for tile t done; 2 newer groups
//                           (t+1,t+2) stay IN FLIGHT across the barrier
//   s_barrier            <- other wave executed the same vmcnt -> its half
//                           of tile t is also complete (m201 discipline)
//   issue stage t+3      <- post-barrier: tile t-1's readers are done
//                           (ds_reads lgkm-waited before their MFMAs, which
//                           precede the barrier in program order)
//   8 x ds_read_b128, 16 MFMA, argmin epilogue
// seb staged once into LDS (4 KB, broadcast-read, conflict-free) so vmcnt
// counts ONLY the 4-gload stage groups.  Never drains vmcnt to 0 in the
// main loop (tails use vmcnt(4)/vmcnt(0)).
// LDS 36 KB -> 4 blocks/CU (= grid) -> 8 waves/CU.
// MFMA layouts (proven R3-R5): A[m=lane&15][k=(lane>>4)*8+j],
// B[n=lane&15][k=same], D col(code)=lane&15, row=(lane>>4)*4+reg.
// argmin key: (bits(se+0.25-2dot) & ~1023) | code -> min_u32. Hist fused.
// ---------------------------------------------------------------------------
__global__ __launch_bounds__(128, 2)
void k_argmin(const float* __restrict__ x,
              const unsigned short* __restrict__ eb,
              const float* __restrict__ seb,
              int* __restrict__ idx_out, int* __restrict__ counts) {
    __shared__ unsigned short bs[4][4096];   // ring: 4 tiles x 8 KB
    __shared__ float ses[NCODE];             // all code norms (+0.25), 4 KB

    const int t = threadIdx.x;
    const int w = t >> 6;            // wave 0/1
    const int l = t & 63;
    const int lr = l & 15;
    const int lh = l >> 4;
    const int row0 = blockIdx.x * 64;

    // --- issue ses stage + first 3 tile stages (order defines vmcnt counts) ---
    {
        const float* ssrc = seb + w * 512 + l * 4;
        #pragma unroll
        for (int i = 0; i < 2; ++i)
            gload_lds16(ssrc + i * 256, &ses[w * 512 + i * 256]);
        #pragma unroll
        for (int p = 0; p < 3; ++p) {
            const unsigned short* src = eb + p * 4096 + w * 2048 + (size_t)l * 8;
            #pragma unroll
            for (int i = 0; i < 4; ++i)
                gload_lds16(src + i * 512, &bs[p][w * 2048 + i * 512]);
        }
    }

    // --- A fragments: 2 stripes x 8 ksteps, fp32 loads + in-reg cvt.
    //     Long HBM latency overlaps the staging issued above; the compiler's
    //     own vmcnt waits for f2bf also drain the stage groups pre-loop,
    //     which only helps the first iterations. ---
    bf16x8 af[2][8];
    #pragma unroll
    for (int s = 0; s < 2; ++s) {
        const float* rp = x + (size_t)(row0 + w * 32 + s * 16 + lr) * DIM + lh * 8;
        #pragma unroll
        for (int ks = 0; ks < 8; ++ks) {
            float4 a = *(const float4*)(rp + ks * 32);
            float4 b = *(const float4*)(rp + ks * 32 + 4);
            bf16x8 o;
            o[0] = (short)f2bf(a.x); o[1] = (short)f2bf(a.y);
            o[2] = (short)f2bf(a.z); o[3] = (short)f2bf(a.w);
            o[4] = (short)f2bf(b.x); o[5] = (short)f2bf(b.y);
            o[6] = (short)f2bf(b.z); o[7] = (short)f2bf(b.w);
            af[s][ks] = o;
        }
    }

    unsigned best[2][4];
    #pragma unroll
    for (int s = 0; s < 2; ++s)
        #pragma unroll
        for (int r = 0; r < 4; ++r) best[s][r] = 0xFFFFFFFFu;

    // one 16-code tile: ds_read bfr from ring slot, 16 MFMA, argmin epilogue
#define COMPUTE_TILE(TI, SLOT) do {                                          \
        const int ti_ = (TI);                                                \
        float sv = ses[ti_ * 16 + lr];                                       \
        const unsigned short* bp = &bs[(SLOT)][0] + l * 8;                   \
        bf16x8 bfr[8];                                                       \
        _Pragma("unroll")                                                    \
        for (int ks = 0; ks < 8; ++ks)                                       \
            bfr[ks] = *(const bf16x8*)(bp + ks * 512);                       \
        f32x4 acc[2];                                                        \
        acc[0] = (f32x4){0.f, 0.f, 0.f, 0.f};                                \
        acc[1] = (f32x4){0.f, 0.f, 0.f, 0.f};                                \
        _Pragma("unroll")                                                    \
        for (int ks = 0; ks < 8; ++ks) {                                     \
            acc[0] = __builtin_amdgcn_mfma_f32_16x16x32_bf16(af[0][ks], bfr[ks], acc[0], 0, 0, 0); \
            acc[1] = __builtin_amdgcn_mfma_f32_16x16x32_bf16(af[1][ks], bfr[ks], acc[1], 0, 0, 0); \
        }                                                                    \
        unsigned nl = (unsigned)(ti_ * 16) | (unsigned)lr;                   \
        _Pragma("unroll")                                                    \
        for (int s = 0; s < 2; ++s)                                          \
            _Pragma("unroll")                                                \
            for (int r = 0; r < 4; ++r) {                                    \
                float sc = fmaf(-2.0f, acc[s][r], sv);                       \
                unsigned u = (__builtin_bit_cast(unsigned, sc) & 0xFFFFFC00u) | nl; \
                best[s][r] = umin_(best[s][r], u);                           \
            }                                                                \
    } while (0)

    #pragma unroll 1
    for (int ti = 0; ti < 62; ++ti) {
        // own stage-group for tile ti complete; groups ti+1, ti+2 (8 ops) in flight
        asm volatile("s_waitcnt vmcnt(8)" ::: "memory");
        __builtin_amdgcn_s_barrier();
        if (ti <= 60) {   // stage tile ti+3 into slot (ti+3)&3 (== (ti-1)&3, now idle)
            const unsigned short* src = eb + (size_t)(ti + 3) * 4096 + w * 2048 + (size_t)l * 8;
            unsigned short* dst = &bs[(ti + 3) & 3][w * 2048];
            #pragma unroll
            for (int i = 0; i < 4; ++i)
                gload_lds16(src + i * 512, dst + i * 512);
        }
        COMPUTE_TILE(ti, ti & 3);
    }
    // tails: drain progressively (62: one group newer; 63: none)
    asm volatile("s_waitcnt vmcnt(4)" ::: "memory");
    __builtin_amdgcn_s_barrier();
    COMPUTE_TILE(62, 2);
    asm volatile("s_waitcnt vmcnt(0)" ::: "memory");
    __builtin_amdgcn_s_barrier();
    COMPUTE_TILE(63, 3);
#undef COMPUTE_TILE

    // reduce over the 16 code-lanes (same lh): xor 1,2,4,8
    #pragma unroll
    for (int s = 0; s < 2; ++s)
        #pragma unroll
        for (int r = 0; r < 4; ++r) {
            unsigned b = best[s][r];
            #pragma unroll
            for (int m = 1; m <= 8; m <<= 1)
                b = umin_(b, (unsigned)__shfl_xor((int)b, m, 64));
            best[s][r] = b;
        }

    if (lr == 0) {
        #pragma unroll
        for (int s = 0; s < 2; ++s)
            #pragma unroll
            for (int r = 0; r < 4; ++r) {
                int code = (int)(best[s][r] & 1023u);
                idx_out[row0 + w * 32 + s * 16 + lh * 4 + r] = code;
                atomicAdd(&counts[code], 1);
            }
    }
}

// ---------------------------------------------------------------------------
// K2: gather + straight-through output + loss sum (fp32 exact).
// Wave owns 8 rows; idx loads, x loads, gathers all issued before use.
// ---------------------------------------------------------------------------
__global__ __launch_bounds__(256)
void k_out_loss(const float* __restrict__ x, const float* __restrict__ e,
                const int* __restrict__ idx, float* __restrict__ out,
                double* __restrict__ sumsq) {
    const int w = threadIdx.x >> 6;
    const int l = threadIdx.x & 63;
    const int row0 = blockIdx.x * 32 + w * 8;

    int k[8];
    #pragma unroll
    for (int r = 0; r < 8; ++r) k[r] = idx[row0 + r];
    float4 xv[8];
    #pragma unroll
    for (int r = 0; r < 8; ++r) xv[r] = ((const float4*)x)[(size_t)(row0 + r) * 64 + l];
    float4 qv[8];
    #pragma unroll
    for (int r = 0; r < 8; ++r) qv[r] = ((const float4*)e)[(size_t)k[r] * 64 + l];

    float local = 0.f;
    #pragma unroll
    for (int r = 0; r < 8; ++r) {
        float4 d, o;
        d.x = qv[r].x - xv[r].x; d.y = qv[r].y - xv[r].y;
        d.z = qv[r].z - xv[r].z; d.w = qv[r].w - xv[r].w;
        o.x = xv[r].x + d.x;  o.y = xv[r].y + d.y;
        o.z = xv[r].z + d.z;  o.w = xv[r].w + d.w;
        ((float4*)out)[(size_t)(row0 + r) * 64 + l] = o;
        local += d.x * d.x + d.y * d.y + d.z * d.z + d.w * d.w;
    }
    #pragma unroll
    for (int m = 32; m >= 1; m >>= 1) local += __shfl_xor(local, m, 64);
    __shared__ float red[4];
    if (l == 0) red[w] = local;
    __syncthreads();
    if (threadIdx.x == 0) {
        float s = red[0] + red[1] + red[2] + red[3];
        atomicAdd(sumsq, (double)s);
    }
}

// ---------------------------------------------------------------------------
// K4: finalize loss + perplexity (single block)
// ---------------------------------------------------------------------------
__global__ __launch_bounds__(256)
void k_fin(const int* __restrict__ counts, const double* __restrict__ sumsq,
           float* __restrict__ out_scalars) {
    float local = 0.f;
    for (int c = threadIdx.x; c < NCODE; c += 256) {
        float p = (float)counts[c] * (1.0f / 65536.0f);
        local += p * logf(p + 1e-10f);
    }
    #pragma unroll
    for (int m = 32; m >= 1; m >>= 1) local += __shfl_xor(local, m, 64);
    __shared__ float red[4];
    if ((threadIdx.x & 63) == 0) red[threadIdx.x >> 6] = local;
    __syncthreads();
    if (threadIdx.x == 0) {
        float s = red[0] + red[1] + red[2] + red[3];
        float perp = expf(-s);
        float m = (float)(*sumsq * (1.0 / 16777216.0));
        float loss = m + 0.25f * m;
        out_scalars[0] = loss;
        out_scalars[1] = perp;
    }
}

// ---------------------------------------------------------------------------
extern "C" void kernel_launch(void* const* d_in, const int* in_sizes, int n_in,
                              void* d_out, int out_size, void* d_ws, size_t ws_size,
                              hipStream_t stream) {
    const float* x   = (const float*)d_in[0];   // [65536, 256]
    const float* emb = (const float*)d_in[1];   // [1024, 256]
    float* out = (float*)d_out;                 // [16777216 + 2]

    // small workspace
    int*    idx    = (int*)d_ws;                            // 256 KB
    float*  seb    = (float*)((char*)d_ws + 262144);        // 4 KB
    int*    counts = (int*)((char*)d_ws + 266240);          // 4 KB
    double* sumsq  = (double*)((char*)d_ws + 270336);       // 8 B

    // eb scratch lives in d_out: consumed by k_argmin BEFORE k_out_loss
    // overwrites d_out (stream-ordered).
    unsigned short* eb = (unsigned short*)((char*)d_out + 33554432); // 512 KB

    hipMemsetAsync((char*)d_ws + 266240, 0, 4096 + 8, stream);

    k_prep    <<<132,        256, 0, stream>>>(emb, seb, eb);
    k_argmin  <<<NROWS / 64, 128, 0, stream>>>(x, eb, seb, idx, counts);
    k_out_loss<<<NROWS / 32, 256, 0, stream>>>(x, emb, idx, out, sumsq);
    k_fin     <<<1,          256, 0, stream>>>(counts, sumsq, out + OUT_ELEMS);
}

// Round 3
// 200.197 us; speedup vs baseline: 1.0820x; 1.0820x over previous
//
#include <hip/hip_runtime.h>
#include <hip/hip_bf16.h>

// Problem constants
#define NROWS 65536      // 64*32*32
#define DIM   256
#define NCODE 1024
#define OUT_ELEMS 16777216  // NROWS*DIM

typedef __attribute__((ext_vector_type(8))) short bf16x8;
typedef __attribute__((ext_vector_type(4))) float f32x4;

__device__ __forceinline__ unsigned umin_(unsigned a, unsigned b) { return a < b ? a : b; }

// RNE float->bf16 (finite inputs) — must stay bit-identical across rounds
__device__ __forceinline__ unsigned short f2bf(float f) {
    unsigned b = __builtin_bit_cast(unsigned, f);
    return (unsigned short)((b + 0x7FFFu + ((b >> 16) & 1u)) >> 16);
}

// ---------------------------------------------------------------------------
// K_prep: blocks 0..127: codebook fp32 -> bf16 in MFMA B-fragment order.
//   eb[((t*8+ks)*64 + lane)*8 + j] = e[n][k], n=t*16+(lane&15), k=ks*32+(lane>>4)*8+j
//   (tile t = 4096 shorts = 8 KB contiguous; fragment for (ks,lane) is 16 B
//   at ((t*8+ks)*64+lane)*16 bytes — consecutive lanes are coalesced 1 KB)
// blocks 128..131: per-code squared norms + 0.25 key offset (fp32 exact).
// ---------------------------------------------------------------------------
__global__ __launch_bounds__(256)
void k_prep(const float* __restrict__ e, float* __restrict__ seb,
            unsigned short* __restrict__ eb) {
    int b = blockIdx.x;
    if (b < 128) {
        int g = b * 256 + threadIdx.x;   // 0 .. 32767
        int lane = g & 63;
        int ks   = (g >> 6) & 7;
        int t    = g >> 9;
        int n  = t * 16 + (lane & 15);
        int k0 = ks * 32 + (lane >> 4) * 8;
        const float* src = e + (size_t)n * DIM + k0;
        bf16x8 o;
        #pragma unroll
        for (int j = 0; j < 8; ++j) o[j] = (short)f2bf(src[j]);
        *(bf16x8*)(eb + (size_t)g * 8) = o;
    } else {
        int c = (b - 128) * 256 + threadIdx.x;
        const float4* r = (const float4*)(e + (size_t)c * DIM);
        float s = 0.f;
        #pragma unroll
        for (int i = 0; i < DIM / 4; ++i) {
            float4 v = r[i];
            s += v.x * v.x + v.y * v.y + v.z * v.z + v.w * v.w;
        }
        seb[c] = s + 0.25f;
    }
}

// ---------------------------------------------------------------------------
// K1 (R3): MFMA distance-argmin, REGISTER-STREAMED B — no LDS, no barriers.
// R2 post-mortem: barrier/rendezvous structure was the tax (counted-vmcnt
// ring REGRESSED).  B (eb, 512 KB) is L2-resident in every XCD, so each
// wave streams its B-fragments straight into VGPRs:
//   - 512 blocks x 256 thr = 4 INDEPENDENT waves/block, 32 rows/wave.
//   - Per 16-code tile: 16 MFMA; B double-buffered in registers (bA/bB,
//     32 VGPR each), refill of tile t+2's fragment issued right after the
//     two MFMAs that consume that ks-slot — ~1.5 tiles (~500 cyc) of MFMA
//     cover for ~200-300 cyc L2 latency.  Compiler manages vmcnt counting
//     (fine-grained, per guide) — zero inline asm, zero sync.
//   - 8 waves/CU (2/SIMD): independent waves co-schedule MFMA/VALU/VMEM.
// L2 traffic: 2048 waves x 512 KB = 1.05 GB (~30 us at L2 BW ceiling).
// MFMA layouts (proven R3-R5): A[m=lane&15][k=(lane>>4)*8+j],
// B[n=lane&15][k=same], D col(code)=lane&15, row=(lane>>4)*4+reg.
// argmin key: (bits(se+0.25-2dot) & ~1023) | code -> min_u32. Hist fused.
// ---------------------------------------------------------------------------
__global__ __launch_bounds__(256, 2)
void k_argmin(const float* __restrict__ x,
              const unsigned short* __restrict__ eb,
              const float* __restrict__ seb,
              int* __restrict__ idx_out, int* __restrict__ counts) {
    const int wid = threadIdx.x >> 6;   // wave 0..3, fully independent
    const int l  = threadIdx.x & 63;
    const int lr = l & 15;
    const int lh = l >> 4;
    const int row0 = blockIdx.x * 128 + wid * 32;

    const bf16x8* __restrict__ ebv = (const bf16x8*)eb;  // fragment units

    // B preload: tiles 0 and 1 into register double-buffer (issue FIRST so
    // they stream behind the A loads' latency)
    bf16x8 bA[8], bB[8];
    #pragma unroll
    for (int ks = 0; ks < 8; ++ks) {
        bA[ks] = ebv[ks * 64 + l];
        bB[ks] = ebv[512 + ks * 64 + l];
    }

    // A fragments: 2 stripes x 8 ksteps (64 VGPR), fp32 loads + in-reg cvt
    bf16x8 af[2][8];
    #pragma unroll
    for (int s = 0; s < 2; ++s) {
        const float* rp = x + (size_t)(row0 + s * 16 + lr) * DIM + lh * 8;
        #pragma unroll
        for (int ks = 0; ks < 8; ++ks) {
            float4 a = *(const float4*)(rp + ks * 32);
            float4 b = *(const float4*)(rp + ks * 32 + 4);
            bf16x8 o;
            o[0] = (short)f2bf(a.x); o[1] = (short)f2bf(a.y);
            o[2] = (short)f2bf(a.z); o[3] = (short)f2bf(a.w);
            o[4] = (short)f2bf(b.x); o[5] = (short)f2bf(b.y);
            o[6] = (short)f2bf(b.z); o[7] = (short)f2bf(b.w);
            af[s][ks] = o;
        }
    }

    unsigned best[2][4];
    #pragma unroll
    for (int s = 0; s < 2; ++s)
        #pragma unroll
        for (int r = 0; r < 4; ++r) best[s][r] = 0xFFFFFFFFu;

    // one tile: sv load (head — L2 latency covered by the 16 MFMAs), 16 MFMA
    // from register buffer B, per-ks refill of tile RT into the same slot
    // (RT < 0 => no refill, for the 2-tile tail), argmin epilogue.
#define PHASE(TI, B, RT) do {                                                \
        const int ti_ = (TI);                                                \
        const int rt_ = (RT);                                                \
        float sv_ = seb[ti_ * 16 + lr];                                      \
        f32x4 a0_ = (f32x4){0.f, 0.f, 0.f, 0.f};                             \
        f32x4 a1_ = (f32x4){0.f, 0.f, 0.f, 0.f};                             \
        _Pragma("unroll")                                                    \
        for (int ks = 0; ks < 8; ++ks) {                                     \
            a0_ = __builtin_amdgcn_mfma_f32_16x16x32_bf16(af[0][ks], B[ks], a0_, 0, 0, 0); \
            a1_ = __builtin_amdgcn_mfma_f32_16x16x32_bf16(af[1][ks], B[ks], a1_, 0, 0, 0); \
            if (rt_ >= 0) B[ks] = ebv[(size_t)rt_ * 512 + ks * 64 + l];      \
        }                                                                    \
        unsigned nl_ = (unsigned)(ti_ * 16) | (unsigned)lr;                  \
        _Pragma("unroll")                                                    \
        for (int r = 0; r < 4; ++r) {                                        \
            float s0_ = fmaf(-2.0f, a0_[r], sv_);                            \
            best[0][r] = umin_(best[0][r],                                   \
                (__builtin_bit_cast(unsigned, s0_) & 0xFFFFFC00u) | nl_);    \
            float s1_ = fmaf(-2.0f, a1_[r], sv_);                            \
            best[1][r] = umin_(best[1][r],                                   \
                (__builtin_bit_cast(unsigned, s1_) & 0xFFFFFC00u) | nl_);    \
        }                                                                    \
    } while (0)

    #pragma unroll 1
    for (int ti = 0; ti < 62; ti += 2) {
        PHASE(ti,     bA, ti + 2);
        PHASE(ti + 1, bB, ti + 3);
    }
    PHASE(62, bA, -1);
    PHASE(63, bB, -1);
#undef PHASE

    // reduce over the 16 code-lanes (same lh): xor 1,2,4,8
    #pragma unroll
    for (int s = 0; s < 2; ++s)
        #pragma unroll
        for (int r = 0; r < 4; ++r) {
            unsigned b = best[s][r];
            #pragma unroll
            for (int m = 1; m <= 8; m <<= 1)
                b = umin_(b, (unsigned)__shfl_xor((int)b, m, 64));
            best[s][r] = b;
        }

    if (lr == 0) {
        #pragma unroll
        for (int s = 0; s < 2; ++s)
            #pragma unroll
            for (int r = 0; r < 4; ++r) {
                int code = (int)(best[s][r] & 1023u);
                idx_out[row0 + s * 16 + lh * 4 + r] = code;
                atomicAdd(&counts[code], 1);
            }
    }
}

// ---------------------------------------------------------------------------
// K2: gather + straight-through output + loss sum (fp32 exact).
// Wave owns 8 rows; idx loads, x loads, gathers all issued before use.
// ---------------------------------------------------------------------------
__global__ __launch_bounds__(256)
void k_out_loss(const float* __restrict__ x, const float* __restrict__ e,
                const int* __restrict__ idx, float* __restrict__ out,
                double* __restrict__ sumsq) {
    const int w = threadIdx.x >> 6;
    const int l = threadIdx.x & 63;
    const int row0 = blockIdx.x * 32 + w * 8;

    int k[8];
    #pragma unroll
    for (int r = 0; r < 8; ++r) k[r] = idx[row0 + r];
    float4 xv[8];
    #pragma unroll
    for (int r = 0; r < 8; ++r) xv[r] = ((const float4*)x)[(size_t)(row0 + r) * 64 + l];
    float4 qv[8];
    #pragma unroll
    for (int r = 0; r < 8; ++r) qv[r] = ((const float4*)e)[(size_t)k[r] * 64 + l];

    float local = 0.f;
    #pragma unroll
    for (int r = 0; r < 8; ++r) {
        float4 d, o;
        d.x = qv[r].x - xv[r].x; d.y = qv[r].y - xv[r].y;
        d.z = qv[r].z - xv[r].z; d.w = qv[r].w - xv[r].w;
        o.x = xv[r].x + d.x;  o.y = xv[r].y + d.y;
        o.z = xv[r].z + d.z;  o.w = xv[r].w + d.w;
        ((float4*)out)[(size_t)(row0 + r) * 64 + l] = o;
        local += d.x * d.x + d.y * d.y + d.z * d.z + d.w * d.w;
    }
    #pragma unroll
    for (int m = 32; m >= 1; m >>= 1) local += __shfl_xor(local, m, 64);
    __shared__ float red[4];
    if (l == 0) red[w] = local;
    __syncthreads();
    if (threadIdx.x == 0) {
        float s = red[0] + red[1] + red[2] + red[3];
        atomicAdd(sumsq, (double)s);
    }
}

// ---------------------------------------------------------------------------
// K4: finalize loss + perplexity (single block)
// ---------------------------------------------------------------------------
__global__ __launch_bounds__(256)
void k_fin(const int* __restrict__ counts, const double* __restrict__ sumsq,
           float* __restrict__ out_scalars) {
    float local = 0.f;
    for (int c = threadIdx.x; c < NCODE; c += 256) {
        float p = (float)counts[c] * (1.0f / 65536.0f);
        local += p * logf(p + 1e-10f);
    }
    #pragma unroll
    for (int m = 32; m >= 1; m >>= 1) local += __shfl_xor(local, m, 64);
    __shared__ float red[4];
    if ((threadIdx.x & 63) == 0) red[threadIdx.x >> 6] = local;
    __syncthreads();
    if (threadIdx.x == 0) {
        float s = red[0] + red[1] + red[2] + red[3];
        float perp = expf(-s);
        float m = (float)(*sumsq * (1.0 / 16777216.0));
        float loss = m + 0.25f * m;
        out_scalars[0] = loss;
        out_scalars[1] = perp;
    }
}

// ---------------------------------------------------------------------------
extern "C" void kernel_launch(void* const* d_in, const int* in_sizes, int n_in,
                              void* d_out, int out_size, void* d_ws, size_t ws_size,
                              hipStream_t stream) {
    const float* x   = (const float*)d_in[0];   // [65536, 256]
    const float* emb = (const float*)d_in[1];   // [1024, 256]
    float* out = (float*)d_out;                 // [16777216 + 2]

    // small workspace
    int*    idx    = (int*)d_ws;                            // 256 KB
    float*  seb    = (float*)((char*)d_ws + 262144);        // 4 KB
    int*    counts = (int*)((char*)d_ws + 266240);          // 4 KB
    double* sumsq  = (double*)((char*)d_ws + 270336);       // 8 B

    // eb scratch lives in d_out: consumed by k_argmin BEFORE k_out_loss
    // overwrites d_out (stream-ordered).
    unsigned short* eb = (unsigned short*)((char*)d_out + 33554432); // 512 KB

    hipMemsetAsync((char*)d_ws + 266240, 0, 4096 + 8, stream);

    k_prep    <<<132,         256, 0, stream>>>(emb, seb, eb);
    k_argmin  <<<NROWS / 128, 256, 0, stream>>>(x, eb, seb, idx, counts);
    k_out_loss<<<NROWS / 32,  256, 0, stream>>>(x, emb, idx, out, sumsq);
    k_fin     <<<1,           256, 0, stream>>>(counts, sumsq, out + OUT_ELEMS);
}

// Round 4
// 181.006 us; speedup vs baseline: 1.1967x; 1.1060x over previous
//
#include <hip/hip_runtime.h>
#include <hip/hip_bf16.h>

// Problem constants
#define NROWS 65536      // 64*32*32
#define DIM   256
#define NCODE 1024
#define OUT_ELEMS 16777216  // NROWS*DIM

typedef __attribute__((ext_vector_type(8))) short bf16x8;
typedef __attribute__((ext_vector_type(4))) float f32x4;

__device__ __forceinline__ unsigned umin_(unsigned a, unsigned b) { return a < b ? a : b; }

// RNE float->bf16 (finite inputs) — must stay bit-identical across rounds
__device__ __forceinline__ unsigned short f2bf(float f) {
    unsigned b = __builtin_bit_cast(unsigned, f);
    return (unsigned short)((b + 0x7FFFu + ((b >> 16) & 1u)) >> 16);
}

// ---------------------------------------------------------------------------
// K_prep: blocks 0..127: codebook fp32 -> bf16 in MFMA B-fragment order.
//   eb[((t*8+ks)*64 + lane)*8 + j] = e[n][k], n=t*16+(lane&15), k=ks*32+(lane>>4)*8+j
// blocks 128..131: per-code squared norms + 0.25 key offset (fp32 exact).
// ---------------------------------------------------------------------------
__global__ __launch_bounds__(256)
void k_prep(const float* __restrict__ e, float* __restrict__ seb,
            unsigned short* __restrict__ eb) {
    int b = blockIdx.x;
    if (b < 128) {
        int g = b * 256 + threadIdx.x;   // 0 .. 32767
        int lane = g & 63;
        int ks   = (g >> 6) & 7;
        int t    = g >> 9;
        int n  = t * 16 + (lane & 15);
        int k0 = ks * 32 + (lane >> 4) * 8;
        const float* src = e + (size_t)n * DIM + k0;
        bf16x8 o;
        #pragma unroll
        for (int j = 0; j < 8; ++j) o[j] = (short)f2bf(src[j]);
        *(bf16x8*)(eb + (size_t)g * 8) = o;
    } else {
        int c = (b - 128) * 256 + threadIdx.x;
        const float4* r = (const float4*)(e + (size_t)c * DIM);
        float s = 0.f;
        #pragma unroll
        for (int i = 0; i < DIM / 4; ++i) {
            float4 v = r[i];
            s += v.x * v.x + v.y * v.y + v.z * v.z + v.w * v.w;
        }
        seb[c] = s + 0.25f;
    }
}

// ---------------------------------------------------------------------------
// K_main (R4): FUSED argmin + gather + straight-through out + loss.
// Core = R3 register-streamed MFMA argmin (best so far; no LDS/barriers in
// the main loop).  After the lane-reduce, each wave broadcasts its 32 codes
// via shfl, gathers e[code] fp32 (1 MB table, L2-hot), re-reads its x rows
// (L3-warm), computes K2's EXACT arithmetic (d=q-x; o=x+d; sum d^2),
// stores out, and block-reduces loss into sumsq (1 double atomic / block).
// Saves: one 64 MB x read, idx round-trip, one launch + gap.
// ALIASING: eb sits at d_out+32MB == out rows [32768,33280) == blocks
// 256..259.  Those blocks SKIP their out-store (other blocks still read eb)
// and record their codes in ws; k_fix rewrites those 512 rows afterwards.
// MFMA layouts (proven): A[m=lane&15][k=(lane>>4)*8+j], B[n=lane&15][k=same],
// D col(code)=lane&15, row=(lane>>4)*4+reg.
// argmin key: (bits(se+0.25-2dot) & ~1023) | code -> min_u32. Hist fused.
// ---------------------------------------------------------------------------
__global__ __launch_bounds__(256, 2)
void k_main(const float* __restrict__ x,
            const float* __restrict__ e,
            const unsigned short* __restrict__ eb,
            const float* __restrict__ seb,
            float* __restrict__ out,
            int* __restrict__ counts,
            double* __restrict__ sumsq,
            int* __restrict__ fixidx) {
    const int wid = threadIdx.x >> 6;   // wave 0..3, fully independent
    const int l  = threadIdx.x & 63;
    const int lr = l & 15;
    const int lh = l >> 4;
    const int row0 = blockIdx.x * 128 + wid * 32;

    const bf16x8* __restrict__ ebv = (const bf16x8*)eb;  // fragment units

    // B preload: tiles 0 and 1 into register double-buffer (issue FIRST)
    bf16x8 bA[8], bB[8];
    #pragma unroll
    for (int ks = 0; ks < 8; ++ks) {
        bA[ks] = ebv[ks * 64 + l];
        bB[ks] = ebv[512 + ks * 64 + l];
    }

    // A fragments: 2 stripes x 8 ksteps, fp32 loads + in-reg cvt
    bf16x8 af[2][8];
    #pragma unroll
    for (int s = 0; s < 2; ++s) {
        const float* rp = x + (size_t)(row0 + s * 16 + lr) * DIM + lh * 8;
        #pragma unroll
        for (int ks = 0; ks < 8; ++ks) {
            float4 a = *(const float4*)(rp + ks * 32);
            float4 b = *(const float4*)(rp + ks * 32 + 4);
            bf16x8 o;
            o[0] = (short)f2bf(a.x); o[1] = (short)f2bf(a.y);
            o[2] = (short)f2bf(a.z); o[3] = (short)f2bf(a.w);
            o[4] = (short)f2bf(b.x); o[5] = (short)f2bf(b.y);
            o[6] = (short)f2bf(b.z); o[7] = (short)f2bf(b.w);
            af[s][ks] = o;
        }
    }

    unsigned best[2][4];
    #pragma unroll
    for (int s = 0; s < 2; ++s)
        #pragma unroll
        for (int r = 0; r < 4; ++r) best[s][r] = 0xFFFFFFFFu;

#define PHASE(TI, B, RT) do {                                                \
        const int ti_ = (TI);                                                \
        const int rt_ = (RT);                                                \
        float sv_ = seb[ti_ * 16 + lr];                                      \
        f32x4 a0_ = (f32x4){0.f, 0.f, 0.f, 0.f};                             \
        f32x4 a1_ = (f32x4){0.f, 0.f, 0.f, 0.f};                             \
        _Pragma("unroll")                                                    \
        for (int ks = 0; ks < 8; ++ks) {                                     \
            a0_ = __builtin_amdgcn_mfma_f32_16x16x32_bf16(af[0][ks], B[ks], a0_, 0, 0, 0); \
            a1_ = __builtin_amdgcn_mfma_f32_16x16x32_bf16(af[1][ks], B[ks], a1_, 0, 0, 0); \
            if (rt_ >= 0) B[ks] = ebv[(size_t)rt_ * 512 + ks * 64 + l];      \
        }                                                                    \
        unsigned nl_ = (unsigned)(ti_ * 16) | (unsigned)lr;                  \
        _Pragma("unroll")                                                    \
        for (int r = 0; r < 4; ++r) {                                        \
            float s0_ = fmaf(-2.0f, a0_[r], sv_);                            \
            best[0][r] = umin_(best[0][r],                                   \
                (__builtin_bit_cast(unsigned, s0_) & 0xFFFFFC00u) | nl_);    \
            float s1_ = fmaf(-2.0f, a1_[r], sv_);                            \
            best[1][r] = umin_(best[1][r],                                   \
                (__builtin_bit_cast(unsigned, s1_) & 0xFFFFFC00u) | nl_);    \
        }                                                                    \
    } while (0)

    #pragma unroll 1
    for (int ti = 0; ti < 62; ti += 2) {
        PHASE(ti,     bA, ti + 2);
        PHASE(ti + 1, bB, ti + 3);
    }
    PHASE(62, bA, -1);
    PHASE(63, bB, -1);
#undef PHASE

    // reduce over the 16 code-lanes (same lh): xor 1,2,4,8
    #pragma unroll
    for (int s = 0; s < 2; ++s)
        #pragma unroll
        for (int r = 0; r < 4; ++r) {
            unsigned b = best[s][r];
            #pragma unroll
            for (int m = 1; m <= 8; m <<= 1)
                b = umin_(b, (unsigned)__shfl_xor((int)b, m, 64));
            best[s][r] = b;
        }

    // eb-overlap blocks: rows [32768,33280) == out bytes [32MB,32.5MB)
    const bool skipout = (blockIdx.x >= 256 && blockIdx.x < 260);

    if (lr == 0) {
        #pragma unroll
        for (int s = 0; s < 2; ++s)
            #pragma unroll
            for (int r = 0; r < 4; ++r) {
                int code = (int)(best[s][r] & 1023u);
                atomicAdd(&counts[code], 1);
                if (skipout)
                    fixidx[row0 + s * 16 + lh * 4 + r - 32768] = code;
            }
    }

    // ---- fused K2 epilogue: 32 rows/wave, in 4 groups of 8 (K2's shape) ----
    float local = 0.f;
    #pragma unroll
    for (int g = 0; g < 4; ++g) {
        int code[8];
        #pragma unroll
        for (int j = 0; j < 8; ++j) {
            const int off = g * 8 + j;
            const int s = off >> 4, h = (off >> 2) & 3, r = off & 3;
            code[j] = (int)((unsigned)__shfl((int)best[s][r], h << 4, 64) & 1023u);
        }
        float4 xv[8];
        #pragma unroll
        for (int j = 0; j < 8; ++j)
            xv[j] = ((const float4*)x)[(size_t)(row0 + g * 8 + j) * 64 + l];
        float4 qv[8];
        #pragma unroll
        for (int j = 0; j < 8; ++j)
            qv[j] = ((const float4*)e)[(size_t)code[j] * 64 + l];
        #pragma unroll
        for (int j = 0; j < 8; ++j) {
            float4 d, o;
            d.x = qv[j].x - xv[j].x; d.y = qv[j].y - xv[j].y;
            d.z = qv[j].z - xv[j].z; d.w = qv[j].w - xv[j].w;
            o.x = xv[j].x + d.x;  o.y = xv[j].y + d.y;
            o.z = xv[j].z + d.z;  o.w = xv[j].w + d.w;
            if (!skipout)
                ((float4*)out)[(size_t)(row0 + g * 8 + j) * 64 + l] = o;
            local += d.x * d.x + d.y * d.y + d.z * d.z + d.w * d.w;
        }
    }
    #pragma unroll
    for (int m = 32; m >= 1; m >>= 1) local += __shfl_xor(local, m, 64);
    __shared__ float red[4];
    if (l == 0) red[wid] = local;
    __syncthreads();
    if (threadIdx.x == 0) {
        float s = red[0] + red[1] + red[2] + red[3];
        atomicAdd(sumsq, (double)s);
    }
}

// ---------------------------------------------------------------------------
// K_fix: rewrite out rows [32768, 33280) (deferred because they alias eb).
// Runs after k_main (stream-ordered; eb dead).  Same arithmetic as epilogue.
// ---------------------------------------------------------------------------
__global__ __launch_bounds__(256)
void k_fix(const float* __restrict__ x, const float* __restrict__ e,
           const int* __restrict__ fixidx, float* __restrict__ out) {
    const int w = threadIdx.x >> 6;
    const int l = threadIdx.x & 63;
    const int rbase = blockIdx.x * 32 + w * 8;   // 0..511 local
    int k[8];
    #pragma unroll
    for (int r = 0; r < 8; ++r) k[r] = fixidx[rbase + r];
    float4 xv[8];
    #pragma unroll
    for (int r = 0; r < 8; ++r)
        xv[r] = ((const float4*)x)[(size_t)(32768 + rbase + r) * 64 + l];
    float4 qv[8];
    #pragma unroll
    for (int r = 0; r < 8; ++r)
        qv[r] = ((const float4*)e)[(size_t)k[r] * 64 + l];
    #pragma unroll
    for (int r = 0; r < 8; ++r) {
        float4 d, o;
        d.x = qv[r].x - xv[r].x; d.y = qv[r].y - xv[r].y;
        d.z = qv[r].z - xv[r].z; d.w = qv[r].w - xv[r].w;
        o.x = xv[r].x + d.x;  o.y = xv[r].y + d.y;
        o.z = xv[r].z + d.z;  o.w = xv[r].w + d.w;
        ((float4*)out)[(size_t)(32768 + rbase + r) * 64 + l] = o;
    }
}

// ---------------------------------------------------------------------------
// K4: finalize loss + perplexity (single block)
// ---------------------------------------------------------------------------
__global__ __launch_bounds__(256)
void k_fin(const int* __restrict__ counts, const double* __restrict__ sumsq,
           float* __restrict__ out_scalars) {
    float local = 0.f;
    for (int c = threadIdx.x; c < NCODE; c += 256) {
        float p = (float)counts[c] * (1.0f / 65536.0f);
        local += p * logf(p + 1e-10f);
    }
    #pragma unroll
    for (int m = 32; m >= 1; m >>= 1) local += __shfl_xor(local, m, 64);
    __shared__ float red[4];
    if ((threadIdx.x & 63) == 0) red[threadIdx.x >> 6] = local;
    __syncthreads();
    if (threadIdx.x == 0) {
        float s = red[0] + red[1] + red[2] + red[3];
        float perp = expf(-s);
        float m = (float)(*sumsq * (1.0 / 16777216.0));
        float loss = m + 0.25f * m;
        out_scalars[0] = loss;
        out_scalars[1] = perp;
    }
}

// ---------------------------------------------------------------------------
extern "C" void kernel_launch(void* const* d_in, const int* in_sizes, int n_in,
                              void* d_out, int out_size, void* d_ws, size_t ws_size,
                              hipStream_t stream) {
    const float* x   = (const float*)d_in[0];   // [65536, 256]
    const float* emb = (const float*)d_in[1];   // [1024, 256]
    float* out = (float*)d_out;                 // [16777216 + 2]

    // small workspace (~11 KB)
    float*  seb    = (float*)d_ws;                          // 4 KB
    int*    counts = (int*)((char*)d_ws + 4096);            // 4 KB
    double* sumsq  = (double*)((char*)d_ws + 8192);         // 8 B
    int*    fixidx = (int*)((char*)d_ws + 8704);            // 2 KB (512 rows)

    // eb scratch lives in d_out at +32MB: read by k_main, whose out-writes
    // SKIP that byte range (blocks 256..259); k_fix patches it afterwards.
    unsigned short* eb = (unsigned short*)((char*)d_out + 33554432); // 512 KB

    hipMemsetAsync((char*)d_ws + 4096, 0, 4104, stream);

    k_prep <<<132,         256, 0, stream>>>(emb, seb, eb);
    k_main <<<NROWS / 128, 256, 0, stream>>>(x, emb, eb, seb, out, counts, sumsq, fixidx);
    k_fix  <<<16,          256, 0, stream>>>(x, emb, fixidx, out);
    k_fin  <<<1,           256, 0, stream>>>(counts, sumsq, out + OUT_ELEMS);
}